// Round 1
// 276.068 us; speedup vs baseline: 1.0076x; 1.0076x over previous
//
#include <hip/hip_runtime.h>

#define NN 50000
#define EE 640000
#define RR 8
#define CAP 64   // per-dst edge capacity; deg ~ Binom(640K, 1/50K), P(deg>=64) ~ 1e-26

typedef __bf16 bf16x8 __attribute__((ext_vector_type(8)));
typedef float  f32x4  __attribute__((ext_vector_type(4)));
typedef const __attribute__((address_space(1))) unsigned int* gas_p;
typedef __attribute__((address_space(3))) unsigned int* las_p;

__device__ __forceinline__ unsigned short f2b(float f) {
  unsigned int u = __float_as_uint(f);
  u += 0x7fffu + ((u >> 16) & 1u);          // round-to-nearest-even
  return (unsigned short)(u >> 16);
}
__device__ __forceinline__ float b2f(unsigned short h) {
  return __uint_as_float(((unsigned int)h) << 16);
}

// ---- f32 -> bf16 bulk convert (x4 vectorized) ----
__global__ void k_f32_to_bf16_x4(const float* __restrict__ src,
                                 unsigned short* __restrict__ dst, int n4) {
  int t = blockIdx.x * blockDim.x + threadIdx.x;
  if (t >= n4) return;
  float4 v = reinterpret_cast<const float4*>(src)[t];
  ushort4 o = make_ushort4(f2b(v.x), f2b(v.y), f2b(v.z), f2b(v.w));
  reinterpret_cast<ushort4*>(dst)[t] = o;
}

// ---- build B^T for layer 1: [1152][128], rows j = r*128+o (r<8) then root ----
__global__ void k_build_b1(const float* __restrict__ W1, const float* __restrict__ root1,
                           unsigned short* __restrict__ B1T) {
  int t = blockIdx.x * 256 + threadIdx.x;
  if (t >= 1152 * 128) return;
  int j = t >> 7, k = t & 127;
  float v = (j < 1024) ? W1[((j >> 7) << 14) + (k << 7) + (j & 127)]
                       : root1[(k << 7) + (j - 1024)];
  B1T[t] = f2b(v);
}

// ---- build B^T for layer 2: [640][128], rows j = r*64+o (r<8), root, zero-pad ----
__global__ void k_build_b2(const float* __restrict__ W2, const float* __restrict__ root2,
                           unsigned short* __restrict__ B2T) {
  int t = blockIdx.x * 256 + threadIdx.x;
  if (t >= 640 * 128) return;
  int j = t >> 7, k = t & 127;
  float v = 0.0f;
  if (j < 512)      v = W2[((j >> 6) << 13) + (k << 6) + (j & 63)];
  else if (j < 576) v = root2[(k << 6) + (j - 512)];
  B2T[t] = f2b(v);
}

// ---- edge pass: per-dst edge-list build (src|r packed); counts come from ballots ----
__global__ void k_edges(const int* __restrict__ src, const int* __restrict__ dst,
                        const int* __restrict__ typ,
                        int* __restrict__ cursor, unsigned int* __restrict__ entries) {
  int e = blockIdx.x * 256 + threadIdx.x;
  if (e >= EE) return;
  int d = dst[e], r = typ[e];
  int pos = atomicAdd(&cursor[d], 1);
  if (pos < CAP)
    entries[d * CAP + pos] = (unsigned int)src[e] | ((unsigned int)r << 16);
}

// ---- bf16 MFMA GEMM: A[M,128] @ B[128, gridDim.y*128] (B given transposed [n][k]).
// N-tiles with n0 <  nsplit  -> Y (bf16, stride nsplit)   [col split is 128-aligned]
// N-tiles with n0 >= nsplit  -> rootOut (f32, stride nroot) + bias; cols >= nroot dropped.
// LDS: XOR-swizzled chunks (16B chunk j stored at j^(row&15)) -> conflict-free frag reads
// Staging: global_load_lds 16B.  Epilogue: swapped-operand MFMA gives each lane 4
// consecutive cols -> pack bf16x4 -> LDS (alias As) -> coalesced 16B global stores.
__global__ __launch_bounds__(256, 2) void k_gemm(
    const unsigned short* __restrict__ A, const unsigned short* __restrict__ BT,
    unsigned short* __restrict__ Y, float* __restrict__ rootOut,
    const float* __restrict__ bias, int M, int nsplit, int nroot) {
  __shared__ __align__(16) unsigned short As[128 * 128];
  __shared__ __align__(16) unsigned short Bs[128 * 128];
  const int tid = threadIdx.x;
  const int m0 = blockIdx.x * 128;
  const int n0 = blockIdx.y * 128;
  const int wv = tid >> 6;
  const int ln = tid & 63;

  // ---- stage 64KB via global_load_lds: wave w covers 64 rows of As (w<2) or Bs ----
  {
    unsigned short* Lbuf = (wv < 2) ? As : Bs;
    const unsigned short* Gbuf = (wv < 2) ? (A + (size_t)m0 * 128) : (BT + (size_t)n0 * 128);
    const int rbase = (wv & 1) * 64;
#pragma unroll
    for (int c = 0; c < 16; ++c) {
      int r = rbase + c * 4 + (ln >> 4);        // row within 128-row buffer
      int c16 = ln & 15;                        // physical 16B chunk
      int j = c16 ^ (r & 15);                   // logical 16B chunk
      const unsigned short* gp = Gbuf + (size_t)r * 128 + j * 8;
      unsigned short* lp = Lbuf + r * 128 + c16 * 8;
      __builtin_amdgcn_global_load_lds((gas_p)(const void*)gp, (las_p)(void*)lp, 16, 0, 0);
    }
  }
  __syncthreads();

  const int lane = tid & 63;
  const int wave = tid >> 6;
  const int wm = (wave >> 1) << 6;
  const int wn = (wave & 1) << 6;
  const int l15 = lane & 15;
  const int quad = lane >> 4;
  f32x4 acc[4][4] = {};
#pragma unroll
  for (int kk = 0; kk < 4; ++kk) {
    const int sw = ((kk * 4 + quad) ^ l15) * 8;   // swizzled byte-chunk offset (shorts)
    bf16x8 af[4], bfr[4];
#pragma unroll
    for (int i = 0; i < 4; ++i) {
      af[i]  = *reinterpret_cast<const bf16x8*>(&As[(wm + i * 16 + l15) * 128 + sw]);
      bfr[i] = *reinterpret_cast<const bf16x8*>(&Bs[(wn + i * 16 + l15) * 128 + sw]);
    }
#pragma unroll
    for (int i = 0; i < 4; ++i)
#pragma unroll
      for (int j = 0; j < 4; ++j)   // swapped operands: lane -> row m, quad*4+r -> col n
        acc[i][j] = __builtin_amdgcn_mfma_f32_16x16x32_bf16(bfr[j], af[i], acc[i][j], 0, 0, 0);
  }

  if (n0 >= nsplit) {
    // ---- root tile: f32 + bias, direct float4 stores ----
#pragma unroll
    for (int i = 0; i < 4; ++i) {
      const int m = wm + i * 16 + l15;
      if (m0 + m >= M) continue;
#pragma unroll
      for (int j = 0; j < 4; ++j) {
        const int col = n0 + wn + j * 16 + quad * 4 - nsplit;
        if (col < nroot) {
          float4 b4 = *reinterpret_cast<const float4*>(&bias[col]);
          float4 v = make_float4(acc[i][j][0] + b4.x, acc[i][j][1] + b4.y,
                                 acc[i][j][2] + b4.z, acc[i][j][3] + b4.w);
          *reinterpret_cast<float4*>(&rootOut[(size_t)(m0 + m) * nroot + col]) = v;
        }
      }
    }
  } else {
    // ---- Y tile: pack bf16x4 -> swizzled LDS (alias As) -> coalesced 16B stores ----
    __syncthreads();                 // all frag reads done; safe to overwrite As
    unsigned short* Cs = As;
#pragma unroll
    for (int i = 0; i < 4; ++i) {
      const int m = wm + i * 16 + l15;
#pragma unroll
      for (int j = 0; j < 4; ++j) {
        const int c8 = ((wn + j * 16) >> 2) + quad;        // logical 8B chunk (0..31)
        const int c8s = c8 ^ (l15 << 1);                   // swizzled
        uint2 pk;
        pk.x = (unsigned int)f2b(acc[i][j][0]) | ((unsigned int)f2b(acc[i][j][1]) << 16);
        pk.y = (unsigned int)f2b(acc[i][j][2]) | ((unsigned int)f2b(acc[i][j][3]) << 16);
        *reinterpret_cast<uint2*>(&Cs[m * 128 + c8s * 4]) = pk;
      }
    }
    __syncthreads();
#pragma unroll
    for (int it = 0; it < 8; ++it) {
      const int L = tid + it * 256;
      const int m = L >> 4;
      const int c16 = L & 15;
      const int c16s = c16 ^ (m & 15);
      if (m0 + m < M) {
        uint4 v = *reinterpret_cast<const uint4*>(&Cs[m * 128 + c16s * 8]);
        *reinterpret_cast<uint4*>(&Y[(size_t)(m0 + m) * nsplit + n0 + c16 * 8]) = v;
      }
    }
  }
}

// ---- layer-1 pull-aggregate: one wave per dst, 128 feats.
// NEW: 16 lanes x 16B per edge -> 4 edges per load instruction, 8 feats/lane,
// unrolled x2 (8 edges / 2KB in flight per wave-iteration). Tail edge slots
// (i >= deg) broadcast entry 0 with sc=0 -> read row 0, contribute nothing.
__global__ void k_agg1(const unsigned int* __restrict__ entries,
                       const int* __restrict__ cursor,
                       const unsigned short* __restrict__ y,
                       const float* __restrict__ hpre,
                       unsigned int* __restrict__ hbf) {
  const int d = blockIdx.x * 4 + (threadIdx.x >> 6);   // NN % 4 == 0
  const int lane = threadIdx.x & 63;
  int deg = cursor[d];
  if (deg > CAP) deg = CAP;
  unsigned int e = (lane < deg) ? entries[d * CAP + lane] : 0u;
  const int myr = (e >> 16) & 7;
  float sc = 0.f;
#pragma unroll
  for (int r = 0; r < 8; ++r) {
    unsigned long long bm = __ballot(lane < deg && myr == r);
    if (myr == r) sc = __builtin_amdgcn_rcpf((float)__popcll(bm));
  }
  if (lane >= deg) sc = 0.f;

  const int g = lane >> 4;    // edge slot within 4-edge pack
  const int l16 = lane & 15;  // feature slice: feats 8*l16 .. 8*l16+7
  float a[8] = {};
  const int T = (deg + 7) >> 3;   // 8 edges per iteration (2x uint4 loads)
  for (int t = 0; t < T; ++t) {
    const int i0 = t * 8 + g;
    const int i1 = i0 + 4;
    unsigned int e0 = __shfl(e, i0, 64);  float s0 = __shfl(sc, i0, 64);
    unsigned int e1 = __shfl(e, i1, 64);  float s1 = __shfl(sc, i1, 64);
    uint4 pk0 = *reinterpret_cast<const uint4*>(
        y + (((size_t)(e0 & 0xffffu)) << 10) + (((e0 >> 16) & 7u) << 7) + (l16 << 3));
    uint4 pk1 = *reinterpret_cast<const uint4*>(
        y + (((size_t)(e1 & 0xffffu)) << 10) + (((e1 >> 16) & 7u) << 7) + (l16 << 3));
    a[0] += b2f((unsigned short)pk0.x) * s0;
    a[1] += __uint_as_float(pk0.x & 0xffff0000u) * s0;
    a[2] += b2f((unsigned short)pk0.y) * s0;
    a[3] += __uint_as_float(pk0.y & 0xffff0000u) * s0;
    a[4] += b2f((unsigned short)pk0.z) * s0;
    a[5] += __uint_as_float(pk0.z & 0xffff0000u) * s0;
    a[6] += b2f((unsigned short)pk0.w) * s0;
    a[7] += __uint_as_float(pk0.w & 0xffff0000u) * s0;
    a[0] += b2f((unsigned short)pk1.x) * s1;
    a[1] += __uint_as_float(pk1.x & 0xffff0000u) * s1;
    a[2] += b2f((unsigned short)pk1.y) * s1;
    a[3] += __uint_as_float(pk1.y & 0xffff0000u) * s1;
    a[4] += b2f((unsigned short)pk1.z) * s1;
    a[5] += __uint_as_float(pk1.z & 0xffff0000u) * s1;
    a[6] += b2f((unsigned short)pk1.w) * s1;
    a[7] += __uint_as_float(pk1.w & 0xffff0000u) * s1;
  }
  // fold the 4 edge-groups (lanes l16, l16+16, l16+32, l16+48 share a feat slice)
#pragma unroll
  for (int j = 0; j < 8; ++j) {
    a[j] += __shfl_xor(a[j], 16, 64);
    a[j] += __shfl_xor(a[j], 32, 64);
  }
  if (g == 0) {
    const float4* hp = reinterpret_cast<const float4*>(hpre) + (size_t)d * 32 + l16 * 2;
    float4 h0 = hp[0];
    float4 h1 = hp[1];
    float v0 = fmaxf(a[0] + h0.x, 0.f), v1 = fmaxf(a[1] + h0.y, 0.f);
    float v2 = fmaxf(a[2] + h0.z, 0.f), v3 = fmaxf(a[3] + h0.w, 0.f);
    float v4 = fmaxf(a[4] + h1.x, 0.f), v5 = fmaxf(a[5] + h1.y, 0.f);
    float v6 = fmaxf(a[6] + h1.z, 0.f), v7 = fmaxf(a[7] + h1.w, 0.f);
    uint4 o;
    o.x = (unsigned int)f2b(v0) | ((unsigned int)f2b(v1) << 16);
    o.y = (unsigned int)f2b(v2) | ((unsigned int)f2b(v3) << 16);
    o.z = (unsigned int)f2b(v4) | ((unsigned int)f2b(v5) << 16);
    o.w = (unsigned int)f2b(v6) | ((unsigned int)f2b(v7) << 16);
    reinterpret_cast<uint4*>(hbf)[(size_t)d * 16 + l16] = o;
  }
}

// ---- layer-2 pull-aggregate + classifier: one wave per dst, 64 feats.
// NEW: 8 lanes x 16B per edge -> 8 edges per load instruction, 8 feats/lane,
// unrolled x2 (16 edges / 2KB in flight per wave-iteration).
__global__ void k_agg2(const unsigned int* __restrict__ entries,
                       const int* __restrict__ cursor,
                       const unsigned short* __restrict__ y,
                       const float* __restrict__ hpre,
                       const float* __restrict__ Wc, const float* __restrict__ bc,
                       float* __restrict__ out) {
  const int d = blockIdx.x * 4 + (threadIdx.x >> 6);
  const int lane = threadIdx.x & 63;
  int deg = cursor[d];
  if (deg > CAP) deg = CAP;
  unsigned int e = (lane < deg) ? entries[d * CAP + lane] : 0u;
  const int myr = (e >> 16) & 7;
  float sc = 0.f;
#pragma unroll
  for (int r = 0; r < 8; ++r) {
    unsigned long long bm = __ballot(lane < deg && myr == r);
    if (myr == r) sc = __builtin_amdgcn_rcpf((float)__popcll(bm));
  }
  if (lane >= deg) sc = 0.f;

  const int g = lane >> 3;   // edge slot within 8-edge pack
  const int l8 = lane & 7;   // feature slice: feats 8*l8 .. 8*l8+7
  float a[8] = {};
  const int T = (deg + 15) >> 4;   // 16 edges per iteration (2x uint4 loads)
  for (int t = 0; t < T; ++t) {
    const int i0 = t * 16 + g;
    const int i1 = i0 + 8;
    unsigned int e0 = __shfl(e, i0, 64);  float s0 = __shfl(sc, i0, 64);
    unsigned int e1 = __shfl(e, i1, 64);  float s1 = __shfl(sc, i1, 64);
    uint4 pk0 = *reinterpret_cast<const uint4*>(
        y + (((size_t)(e0 & 0xffffu)) << 9) + (((e0 >> 16) & 7u) << 6) + (l8 << 3));
    uint4 pk1 = *reinterpret_cast<const uint4*>(
        y + (((size_t)(e1 & 0xffffu)) << 9) + (((e1 >> 16) & 7u) << 6) + (l8 << 3));
    a[0] += b2f((unsigned short)pk0.x) * s0;
    a[1] += __uint_as_float(pk0.x & 0xffff0000u) * s0;
    a[2] += b2f((unsigned short)pk0.y) * s0;
    a[3] += __uint_as_float(pk0.y & 0xffff0000u) * s0;
    a[4] += b2f((unsigned short)pk0.z) * s0;
    a[5] += __uint_as_float(pk0.z & 0xffff0000u) * s0;
    a[6] += b2f((unsigned short)pk0.w) * s0;
    a[7] += __uint_as_float(pk0.w & 0xffff0000u) * s0;
    a[0] += b2f((unsigned short)pk1.x) * s1;
    a[1] += __uint_as_float(pk1.x & 0xffff0000u) * s1;
    a[2] += b2f((unsigned short)pk1.y) * s1;
    a[3] += __uint_as_float(pk1.y & 0xffff0000u) * s1;
    a[4] += b2f((unsigned short)pk1.z) * s1;
    a[5] += __uint_as_float(pk1.z & 0xffff0000u) * s1;
    a[6] += b2f((unsigned short)pk1.w) * s1;
    a[7] += __uint_as_float(pk1.w & 0xffff0000u) * s1;
  }
  // fold the 8 edge-groups: lanes sharing l8 sum up -> every lane has its slice total
#pragma unroll
  for (int j = 0; j < 8; ++j) {
    a[j] += __shfl_xor(a[j], 8, 64);
    a[j] += __shfl_xor(a[j], 16, 64);
    a[j] += __shfl_xor(a[j], 32, 64);
  }
  const float4* hp = reinterpret_cast<const float4*>(hpre) + (size_t)d * 16 + l8 * 2;
  float4 h0 = hp[0];
  float4 h1 = hp[1];
  float v0 = fmaxf(a[0] + h0.x, 0.f), v1 = fmaxf(a[1] + h0.y, 0.f);
  float v2 = fmaxf(a[2] + h0.z, 0.f), v3 = fmaxf(a[3] + h0.w, 0.f);
  float v4 = fmaxf(a[4] + h1.x, 0.f), v5 = fmaxf(a[5] + h1.y, 0.f);
  float v6 = fmaxf(a[6] + h1.z, 0.f), v7 = fmaxf(a[7] + h1.w, 0.f);
  // classifier: Wc is [64][2] f32; float4 w covers feats (f, f+1) x 2 outputs
  const float4* wc4 = reinterpret_cast<const float4*>(Wc) + l8 * 4;
  float4 w0 = wc4[0], w1 = wc4[1], w2 = wc4[2], w3 = wc4[3];
  float p0 = v0 * w0.x + v1 * w0.z + v2 * w1.x + v3 * w1.z
           + v4 * w2.x + v5 * w2.z + v6 * w3.x + v7 * w3.z;
  float p1 = v0 * w0.y + v1 * w0.w + v2 * w1.y + v3 * w1.w
           + v4 * w2.y + v5 * w2.w + v6 * w3.y + v7 * w3.w;
  // reduce over the 8 feat-slices (values depend only on l8)
  p0 += __shfl_xor(p0, 1, 64); p1 += __shfl_xor(p1, 1, 64);
  p0 += __shfl_xor(p0, 2, 64); p1 += __shfl_xor(p1, 2, 64);
  p0 += __shfl_xor(p0, 4, 64); p1 += __shfl_xor(p1, 4, 64);
  if (lane == 0) {
    out[d * 2 + 0] = p0 + bc[0];
    out[d * 2 + 1] = p1 + bc[1];
  }
}

extern "C" void kernel_launch(void* const* d_in, const int* in_sizes, int n_in,
                              void* d_out, int out_size, void* d_ws, size_t ws_size,
                              hipStream_t stream) {
  const float* x     = (const float*)d_in[0];
  const int*   ei    = (const int*)d_in[1];
  const int*   et    = (const int*)d_in[2];
  const float* W1    = (const float*)d_in[3];
  const float* root1 = (const float*)d_in[4];
  const float* b1    = (const float*)d_in[5];
  const float* W2    = (const float*)d_in[6];
  const float* root2 = (const float*)d_in[7];
  const float* b2    = (const float*)d_in[8];
  const float* Wc    = (const float*)d_in[9];
  const float* bc    = (const float*)d_in[10];
  const int* srcI = ei;        // edge_index[0]
  const int* dstI = ei + EE;   // edge_index[1]

  char* ws = (char*)d_ws;
  unsigned short* xb      = (unsigned short*)(ws);             // 12,800,000 B
  unsigned int*   hbf     = (unsigned int*)(ws);               // alias (xb dead after gemm1)
  unsigned short* B1T     = (unsigned short*)(ws + 12800000);  //    294,912 B
  unsigned short* B2T     = (unsigned short*)(ws + 13094912);  //    163,840 B
  int*            cursor  = (int*)(ws + 13258752);             //    200,000 B
  unsigned int*   entries = (unsigned int*)(ws + 13458752);    // 12,800,000 B (50000*64*4)
  float*          hpre    = (float*)(ws + 26258752);           // 25,600,000 B (reused layer 2)
  unsigned short* y1      = (unsigned short*)(ws + 51858752);  // 102,400,000 B
  unsigned short* y2      = y1;                                // alias (y1 dead after agg1)
  // total: 154,258,752 B

  hipMemsetAsync(cursor, 0, 200000, stream);
  k_f32_to_bf16_x4<<<(1600000 + 255) / 256, 256, 0, stream>>>(x, xb, 1600000);
  k_build_b1<<<(1152 * 128 + 255) / 256, 256, 0, stream>>>(W1, root1, B1T);
  k_build_b2<<<(640 * 128 + 255) / 256, 256, 0, stream>>>(W2, root2, B2T);
  k_edges<<<(EE + 255) / 256, 256, 0, stream>>>(srcI, dstI, et, cursor, entries);

  // layer 1: y1 = xb @ [W1_0..W1_7] (bf16), hpre = xb @ root1 + b1 (f32)
  k_gemm<<<dim3(391, 9), 256, 0, stream>>>(xb, B1T, y1, hpre, b1, NN, 1024, 128);
  k_agg1<<<NN / 4, 256, 0, stream>>>(entries, cursor, y1, hpre, hbf);

  // layer 2: y2 = hbf @ [W2_0..W2_7] (bf16), hpre = hbf @ root2 + b2 (f32)
  k_gemm<<<dim3(391, 5), 256, 0, stream>>>((const unsigned short*)hbf, B2T, y2, hpre, b2, NN, 512, 64);
  k_agg2<<<NN / 4, 256, 0, stream>>>(entries, cursor, y2, hpre, Wc, bc, (float*)d_out);
}